// Round 8
// baseline (153.719 us; speedup 1.0000x reference)
//
#include <hip/hip_runtime.h>
#include <hip/hip_bf16.h>

// Problem constants
#define SEQ   4096
#define DM    1024
#define NH    16
#define HD    64
#define N3    3072       // 3*DM
#define WIN   512

#define LOG2E 1.4426950408889634f

typedef __attribute__((ext_vector_type(8))) short short8;   // 8 bf16 (4 VGPRs)
typedef __attribute__((ext_vector_type(4))) short short4v;  // 8B half-frag
typedef __attribute__((ext_vector_type(4))) float float4v;  // 4 fp32 acc

__device__ __forceinline__ float bf16_bits_to_float(unsigned short u) {
  return __uint_as_float(((unsigned int)u) << 16);
}

// async 16B global->LDS (m97 path: emits global_load_lds_dwordx4)
typedef __attribute__((address_space(3))) void lds_void_t;
typedef __attribute__((address_space(1))) const void gbl_void_t;
__device__ __forceinline__ void async_copy16(void* lds_dst, const void* g_src) {
  __builtin_amdgcn_global_load_lds((gbl_void_t*)g_src, (lds_void_t*)lds_dst,
                                   16, 0, 0);
}

// ---------------------------------------------------------------------------
// Per-block dtype detection (nt = blockDim.x, power of 2). fp32 data viewed
// as bf16 half-words has uniform-random exponents -> max >> 100; genuine
// bf16 stays < 100. Returns 1 = fp32 inputs, 0 = bf16.
// ---------------------------------------------------------------------------
template <int NT>
__device__ __forceinline__ int detect_fp32(const unsigned short* __restrict__ probe,
                                           float* red) {
  const int t = threadIdx.x;
  float mx = 0.0f;
#pragma unroll
  for (int p = 0; p < 8; ++p) {
    float v = bf16_bits_to_float(probe[(t * 8 + p) * 2]);
    if (v != v) v = 1e38f;
    mx = fmaxf(mx, fabsf(v));
  }
  red[t] = mx;
  __syncthreads();
  for (int s = NT / 2; s > 0; s >>= 1) {
    if (t < s) red[t] = fmaxf(red[t], red[t + s]);
    __syncthreads();
  }
  const int fl = red[0] > 100.0f ? 1 : 0;
  __syncthreads();
  return fl;
}

// ---------------------------------------------------------------------------
// Kernel 1 (merged prep): blocks [0,2048) convert X -> xb bf16;
// blocks [2048, 2816) transpose/convert W -> WT bf16.
// ---------------------------------------------------------------------------
__global__ __launch_bounds__(256) void prep(
    const void* __restrict__ x, const void* __restrict__ w,
    __hip_bfloat16* __restrict__ xb, __hip_bfloat16* __restrict__ wt) {
  __shared__ __hip_bfloat16 tile[64][66];
  __shared__ float red[256];
  const int t = threadIdx.x;
  if (blockIdx.x < 2048) {
    const int fl = detect_fp32<256>((const unsigned short*)x, red);
    const int i0 = (blockIdx.x * 256 + t) * 8;
    if (fl) {
      const float* xf = (const float*)x + i0;
      float4 f0 = *(const float4*)(xf);
      float4 f1 = *(const float4*)(xf + 4);
      __hip_bfloat16 tmp[8];
      tmp[0] = __float2bfloat16(f0.x); tmp[1] = __float2bfloat16(f0.y);
      tmp[2] = __float2bfloat16(f0.z); tmp[3] = __float2bfloat16(f0.w);
      tmp[4] = __float2bfloat16(f1.x); tmp[5] = __float2bfloat16(f1.y);
      tmp[6] = __float2bfloat16(f1.z); tmp[7] = __float2bfloat16(f1.w);
      *(uint4*)&xb[i0] = *(const uint4*)tmp;
    } else {
      *(uint4*)&xb[i0] = *(const uint4*)((const __hip_bfloat16*)x + i0);
    }
  } else {
    const int bid = blockIdx.x - 2048;
    const int fl = detect_fp32<256>((const unsigned short*)w, red);
    const int n0 = (bid % 48) * 64;
    const int k0 = (bid / 48) * 64;
    const int tx = t & 63, ty0 = t >> 6;
    if (fl) {
      const float* wf = (const float*)w;
#pragma unroll
      for (int p = 0; p < 16; ++p) {
        int row = ty0 + p * 4;
        tile[row][tx] = __float2bfloat16(wf[(k0 + row) * N3 + n0 + tx]);
      }
    } else {
      const __hip_bfloat16* wb = (const __hip_bfloat16*)w;
#pragma unroll
      for (int p = 0; p < 16; ++p) {
        int row = ty0 + p * 4;
        tile[row][tx] = wb[(k0 + row) * N3 + n0 + tx];
      }
    }
    __syncthreads();
#pragma unroll
    for (int r = 0; r < 2; ++r) {
      int oe = r * 2048 + t * 8;
      int nr = oe >> 6, kc = oe & 63;
      __hip_bfloat16 v[8];
#pragma unroll
      for (int e = 0; e < 8; ++e) v[e] = tile[kc + e][nr];
      *(uint4*)&wt[(n0 + nr) * DM + k0 + kc] = *(const uint4*)v;
    }
  }
}

// ---------------------------------------------------------------------------
// Kernel 2: KQV = xb[4096,1024] * W -> bf16 [4096,3072]. BK=64 via two
// ping-pong 128x32 buffer pairs (unchanged from Round 7 — near the m97
// structural plateau for this K).
// ---------------------------------------------------------------------------
__global__ __launch_bounds__(256) void gemm_kqv(
    const __hip_bfloat16* __restrict__ A,    // xb [4096][1024]
    const __hip_bfloat16* __restrict__ BT,   // WT [3072][1024]
    __hip_bfloat16* __restrict__ C) {        // kqv [4096][3072]
  __shared__ __align__(16) __hip_bfloat16 As[2][128 * 32];
  __shared__ __align__(16) __hip_bfloat16 Bs[2][128 * 32];
  const int m0 = blockIdx.y * 128;
  const int n0 = blockIdx.x * 128;
  const int t = threadIdx.x;
  const int wave = t >> 6, lane = t & 63;
  const int wm = wave >> 1, wn = wave & 1;
  const int l15 = lane & 15, quad = lane >> 4;

  const int srow0 = wave * 16 + (lane >> 2);
  const int scol  = (lane & 3) * 8;
  const int sbyte = wave * 1024 + lane * 16;

  float4v acc[4][4] = {};

  for (int k0 = 0; k0 < DM; k0 += 64) {
    __syncthreads();
#pragma unroll
    for (int half = 0; half < 2; ++half) {
      const int kk = k0 + half * 32;
#pragma unroll
      for (int r = 0; r < 2; ++r) {
        const int row = srow0 + r * 64;
        async_copy16((char*)As[half] + r * 4096 + sbyte,
                     &A[(m0 + row) * DM + kk + scol]);
        async_copy16((char*)Bs[half] + r * 4096 + sbyte,
                     &BT[(n0 + row) * DM + kk + scol]);
      }
    }
    __syncthreads();

#pragma unroll
    for (int half = 0; half < 2; ++half) {
      short8 a[4], b[4];
#pragma unroll
      for (int mi = 0; mi < 4; ++mi)
        a[mi] = *(const short8*)(&As[half][(wm * 64 + mi * 16 + l15) * 32 + quad * 8]);
#pragma unroll
      for (int ni = 0; ni < 4; ++ni)
        b[ni] = *(const short8*)(&Bs[half][(wn * 64 + ni * 16 + l15) * 32 + quad * 8]);
#pragma unroll
      for (int mi = 0; mi < 4; ++mi)
#pragma unroll
        for (int ni = 0; ni < 4; ++ni)
          acc[mi][ni] = __builtin_amdgcn_mfma_f32_16x16x32_bf16(
              a[mi], b[ni], acc[mi][ni], 0, 0, 0);
    }
  }

#pragma unroll
  for (int mi = 0; mi < 4; ++mi)
#pragma unroll
    for (int ni = 0; ni < 4; ++ni)
#pragma unroll
      for (int r = 0; r < 4; ++r) {
        int row = m0 + wm * 64 + mi * 16 + quad * 4 + r;
        int col = n0 + wn * 64 + ni * 16 + l15;
        C[row * N3 + col] = __float2bfloat16(acc[mi][ni][r]);
      }
}

// ---------------------------------------------------------------------------
// Kernel 3: MFMA flash attention, fixed-max softmax (m=0).
// ROUND 8: 128-query tiles, 512 threads (8 waves; wave w owns rows w*16..+15).
// Each staged (K,V) key-block now serves 128 queries instead of 64:
// staging bytes, transpose ds-writes, and barriers per unit work drop ~0.55x.
// l (row-sum of P) still computed by MFMA via ones-row in Vt (dt=4).
// Ps strips wave-private -> no softmax barrier. 2 barriers/iter.
// LDS: Ks 9.2K + Vt 10.9K + Ps 18.4K + red 2K = 39.6 KB -> 2 blocks/CU.
// ---------------------------------------------------------------------------
__global__ __launch_bounds__(512, 4) void attn(
    const __hip_bfloat16* __restrict__ kqv,
    const unsigned short* __restrict__ xprobe,   // d_in[0], dtype probe only
    void* __restrict__ out) {
  __shared__ __align__(16) __hip_bfloat16 Ks[64 * 72];   // [k][d]
  __shared__ __align__(16) __hip_bfloat16 Vt[80 * 68];   // [d][key]; row 64 ones, 65..79 zero
  __shared__ __align__(16) __hip_bfloat16 Ps[128 * 72];  // [q][key] (wave-private strips)
  __shared__ float red[512];

  const int fl = detect_fp32<512>(xprobe, red);
  const int h  = blockIdx.y;
  const int i0 = blockIdx.x * 128;
  const int t    = threadIdx.x;
  const int wave = t >> 6, lane = t & 63;
  const int l15 = lane & 15, quad = lane >> 4;
  const float slope2 = exp2f(-0.5f * (float)(h + 1)) * LOG2E;  // m_h*log2(e)
  const float qscale = LOG2E / 32.0f;

  // ones/zero rows of Vt (staging only touches rows 0..63)
  for (int idx = t; idx < 16 * 68; idx += 512) {
    int rr = idx / 68, cc = idx - rr * 68;
    ((unsigned short*)Vt)[(64 + rr) * 68 + cc] = (rr == 0) ? 0x3F80 : 0;
  }

  // Q fragments direct to registers: rows i0 + wave*16 + l15 (covers 128 rows)
  short8 aq[2];
#pragma unroll
  for (int ks2 = 0; ks2 < 2; ++ks2)
    aq[ks2] = *(const short8*)&kqv[(i0 + wave * 16 + l15) * N3 + DM + h * HD +
                                   ks2 * 32 + quad * 8];

  float4v o[5] = {};   // o[dt][r]: row quad*4+r, col dt*16+l15; dt=4 is l-column

  const int jlo  = max(0, i0 - WIN);        // 64-aligned
  const int nblk = (i0 + 128 - jlo) >> 6;   // <= 10

  for (int b = 0; b < nblk; ++b) {
    const int j0 = jlo + b * 64;
    __syncthreads();   // prev iter's K/V readers done before overwrite
    // stage K rows [k][d]: 512 chunks, 1 per thread
    {
      int row = t >> 3, d0 = (t & 7) * 8;
      *(uint4*)&Ks[row * 72 + d0] =
          *(const uint4*)&kqv[(j0 + row) * N3 + h * HD + d0];
    }
    // stage V transposed: thread owns (row-pair t>>4, 4 d-cols), packs 2 keys/dword
    {
      int r0 = (t >> 4) * 2, d0 = (t & 15) * 4;
      uint2 va = *(const uint2*)&kqv[(j0 + r0) * N3 + 2 * DM + h * HD + d0];
      uint2 vb = *(const uint2*)&kqv[(j0 + r0 + 1) * N3 + 2 * DM + h * HD + d0];
      const unsigned short* pa = (const unsigned short*)&va;
      const unsigned short* pb = (const unsigned short*)&vb;
#pragma unroll
      for (int e = 0; e < 4; ++e) {
        unsigned int pack = (unsigned int)pa[e] | ((unsigned int)pb[e] << 16);
        *(unsigned int*)&Vt[(d0 + e) * 68 + r0] = pack;
      }
    }
    __syncthreads();

    // ---- S = Q*K^T : 4 n-tiles x 2 k-steps ----
    float4v sacc[4] = {};
#pragma unroll
    for (int ks2 = 0; ks2 < 2; ++ks2)
#pragma unroll
      for (int nt = 0; nt < 4; ++nt) {
        short8 bk = *(const short8*)&Ks[(nt * 16 + l15) * 72 + ks2 * 32 + quad * 8];
        sacc[nt] = __builtin_amdgcn_mfma_f32_16x16x32_bf16(aq[ks2], bk, sacc[nt], 0, 0, 0);
      }

    // ---- fixed-max softmax: p = exp2(x), masked -> 0; no reductions ----
#pragma unroll
    for (int r = 0; r < 4; ++r) {
      const int i = i0 + wave * 16 + quad * 4 + r;
#pragma unroll
      for (int nt = 0; nt < 4; ++nt) {
        const int j = j0 + nt * 16 + l15;
        const int rel = i - j;
        float x = sacc[nt][r] * qscale + slope2 * (float)(j - i);
        x = (rel >= 0 && rel <= WIN) ? x : -200.0f;   // exp2(-200) == 0
        Ps[(wave * 16 + quad * 4 + r) * 72 + nt * 16 + l15] =
            __float2bfloat16(exp2f(x));
      }
    }
    // no barrier: Ps strip is wave-private

    // ---- O += P*V (dt 0..3) ; l += P*1 (dt 4, ones-row of Vt) ----
#pragma unroll
    for (int ks = 0; ks < 64; ks += 32) {
      short8 ap = *(const short8*)&Ps[(wave * 16 + l15) * 72 + ks + quad * 8];
#pragma unroll
      for (int dt = 0; dt < 5; ++dt) {
        const __hip_bfloat16* vp = &Vt[(dt * 16 + l15) * 68 + ks + quad * 8];
        short4v v0 = *(const short4v*)vp;
        short4v v1 = *(const short4v*)(vp + 4);
        short8 bv;
#pragma unroll
        for (int e = 0; e < 4; ++e) { bv[e] = v0[e]; bv[4 + e] = v1[e]; }
        o[dt] = __builtin_amdgcn_mfma_f32_16x16x32_bf16(ap, bv, o[dt], 0, 0, 0);
      }
    }
  }

  // ---- epilogue: l lives in o[4] col 0 (lane l15==0 of each quad group) ----
#pragma unroll
  for (int r = 0; r < 4; ++r) {
    const float l = __shfl(o[4][r], quad * 16, 64);   // broadcast from l15==0 lane
    const float inv_l = 1.0f / l;    // l >= 2^-2: diagonal key j=i always valid
    const int row = i0 + wave * 16 + quad * 4 + r;
#pragma unroll
    for (int dt = 0; dt < 4; ++dt) {
      const int idx = row * DM + h * HD + dt * 16 + l15;
      const float v = o[dt][r] * inv_l;
      if (fl) ((float*)out)[idx] = v;
      else    ((__hip_bfloat16*)out)[idx] = __float2bfloat16(v);
    }
  }
}

// ---------------------------------------------------------------------------
extern "C" void kernel_launch(void* const* d_in, const int* in_sizes, int n_in,
                              void* d_out, int out_size, void* d_ws, size_t ws_size,
                              hipStream_t stream) {
  char* ws = (char*)d_ws;
  __hip_bfloat16* wt  = (__hip_bfloat16*)(ws + 4096);          // 6 MB
  __hip_bfloat16* kqv = (__hip_bfloat16*)(ws + 4096 + 6291456);// 24 MB
  // xb lives in d_out's first 8 MB: dead until attn's epilogue overwrites all
  // of d_out, and gemm_kqv (the only xb reader) completes before attn runs.
  __hip_bfloat16* xb  = (__hip_bfloat16*)d_out;

  hipLaunchKernelGGL(prep, dim3(2048 + 768), dim3(256), 0, stream,
                     d_in[0], d_in[1], xb, wt);
  hipLaunchKernelGGL(gemm_kqv, dim3(24, 32), dim3(256), 0, stream, xb, wt, kqv);
  hipLaunchKernelGGL(attn, dim3(32, 16), dim3(512), 0, stream,
                     kqv, (const unsigned short*)d_in[0], d_out);
}

// Round 9
// 148.875 us; speedup vs baseline: 1.0325x; 1.0325x over previous
//
#include <hip/hip_runtime.h>
#include <hip/hip_bf16.h>

// Problem constants
#define SEQ   4096
#define DM    1024
#define NH    16
#define HD    64
#define N3    3072       // 3*DM
#define WIN   512

#define LOG2E 1.4426950408889634f

typedef __attribute__((ext_vector_type(8))) short short8;   // 8 bf16 (4 VGPRs)
typedef __attribute__((ext_vector_type(4))) short short4v;  // 8B half-frag
typedef __attribute__((ext_vector_type(4))) float float4v;  // 4 fp32 acc

__device__ __forceinline__ float bf16_bits_to_float(unsigned short u) {
  return __uint_as_float(((unsigned int)u) << 16);
}

// async 16B global->LDS (m97 path: emits global_load_lds_dwordx4)
typedef __attribute__((address_space(3))) void lds_void_t;
typedef __attribute__((address_space(1))) const void gbl_void_t;
__device__ __forceinline__ void async_copy16(void* lds_dst, const void* g_src) {
  __builtin_amdgcn_global_load_lds((gbl_void_t*)g_src, (lds_void_t*)lds_dst,
                                   16, 0, 0);
}

// ---------------------------------------------------------------------------
// Per-block dtype detection. fp32 data viewed as bf16 half-words has
// uniform-random exponents -> max >> 100; genuine bf16 stays < 100.
// Returns 1 = fp32 inputs, 0 = bf16.
// ---------------------------------------------------------------------------
template <int NT>
__device__ __forceinline__ int detect_fp32(const unsigned short* __restrict__ probe,
                                           float* red) {
  const int t = threadIdx.x;
  float mx = 0.0f;
#pragma unroll
  for (int p = 0; p < 8; ++p) {
    float v = bf16_bits_to_float(probe[(t * 8 + p) * 2]);
    if (v != v) v = 1e38f;
    mx = fmaxf(mx, fabsf(v));
  }
  red[t] = mx;
  __syncthreads();
  for (int s = NT / 2; s > 0; s >>= 1) {
    if (t < s) red[t] = fmaxf(red[t], red[t + s]);
    __syncthreads();
  }
  const int fl = red[0] > 100.0f ? 1 : 0;
  __syncthreads();
  return fl;
}

// ---------------------------------------------------------------------------
// Kernel 1 (merged prep): blocks [0,2048) convert X -> xb bf16;
// blocks [2048, 2816) transpose/convert W -> WT bf16.
// ---------------------------------------------------------------------------
__global__ __launch_bounds__(256) void prep(
    const void* __restrict__ x, const void* __restrict__ w,
    __hip_bfloat16* __restrict__ xb, __hip_bfloat16* __restrict__ wt) {
  __shared__ __hip_bfloat16 tile[64][66];
  __shared__ float red[256];
  const int t = threadIdx.x;
  if (blockIdx.x < 2048) {
    const int fl = detect_fp32<256>((const unsigned short*)x, red);
    const int i0 = (blockIdx.x * 256 + t) * 8;
    if (fl) {
      const float* xf = (const float*)x + i0;
      float4 f0 = *(const float4*)(xf);
      float4 f1 = *(const float4*)(xf + 4);
      __hip_bfloat16 tmp[8];
      tmp[0] = __float2bfloat16(f0.x); tmp[1] = __float2bfloat16(f0.y);
      tmp[2] = __float2bfloat16(f0.z); tmp[3] = __float2bfloat16(f0.w);
      tmp[4] = __float2bfloat16(f1.x); tmp[5] = __float2bfloat16(f1.y);
      tmp[6] = __float2bfloat16(f1.z); tmp[7] = __float2bfloat16(f1.w);
      *(uint4*)&xb[i0] = *(const uint4*)tmp;
    } else {
      *(uint4*)&xb[i0] = *(const uint4*)((const __hip_bfloat16*)x + i0);
    }
  } else {
    const int bid = blockIdx.x - 2048;
    const int fl = detect_fp32<256>((const unsigned short*)w, red);
    const int n0 = (bid % 48) * 64;
    const int k0 = (bid / 48) * 64;
    const int tx = t & 63, ty0 = t >> 6;
    if (fl) {
      const float* wf = (const float*)w;
#pragma unroll
      for (int p = 0; p < 16; ++p) {
        int row = ty0 + p * 4;
        tile[row][tx] = __float2bfloat16(wf[(k0 + row) * N3 + n0 + tx]);
      }
    } else {
      const __hip_bfloat16* wb = (const __hip_bfloat16*)w;
#pragma unroll
      for (int p = 0; p < 16; ++p) {
        int row = ty0 + p * 4;
        tile[row][tx] = wb[(k0 + row) * N3 + n0 + tx];
      }
    }
    __syncthreads();
#pragma unroll
    for (int r = 0; r < 2; ++r) {
      int oe = r * 2048 + t * 8;
      int nr = oe >> 6, kc = oe & 63;
      __hip_bfloat16 v[8];
#pragma unroll
      for (int e = 0; e < 8; ++e) v[e] = tile[kc + e][nr];
      *(uint4*)&wt[(n0 + nr) * DM + k0 + kc] = *(const uint4*)v;
    }
  }
}

// ---------------------------------------------------------------------------
// Kernel 2: KQV = xb[4096,1024] * W -> bf16 [4096,3072]. BK=64 via two
// ping-pong 128x32 buffer pairs (unchanged — near the m97 plateau).
// ---------------------------------------------------------------------------
__global__ __launch_bounds__(256) void gemm_kqv(
    const __hip_bfloat16* __restrict__ A,    // xb [4096][1024]
    const __hip_bfloat16* __restrict__ BT,   // WT [3072][1024]
    __hip_bfloat16* __restrict__ C) {        // kqv [4096][3072]
  __shared__ __align__(16) __hip_bfloat16 As[2][128 * 32];
  __shared__ __align__(16) __hip_bfloat16 Bs[2][128 * 32];
  const int m0 = blockIdx.y * 128;
  const int n0 = blockIdx.x * 128;
  const int t = threadIdx.x;
  const int wave = t >> 6, lane = t & 63;
  const int wm = wave >> 1, wn = wave & 1;
  const int l15 = lane & 15, quad = lane >> 4;

  const int srow0 = wave * 16 + (lane >> 2);
  const int scol  = (lane & 3) * 8;
  const int sbyte = wave * 1024 + lane * 16;

  float4v acc[4][4] = {};

  for (int k0 = 0; k0 < DM; k0 += 64) {
    __syncthreads();
#pragma unroll
    for (int half = 0; half < 2; ++half) {
      const int kk = k0 + half * 32;
#pragma unroll
      for (int r = 0; r < 2; ++r) {
        const int row = srow0 + r * 64;
        async_copy16((char*)As[half] + r * 4096 + sbyte,
                     &A[(m0 + row) * DM + kk + scol]);
        async_copy16((char*)Bs[half] + r * 4096 + sbyte,
                     &BT[(n0 + row) * DM + kk + scol]);
      }
    }
    __syncthreads();

#pragma unroll
    for (int half = 0; half < 2; ++half) {
      short8 a[4], b[4];
#pragma unroll
      for (int mi = 0; mi < 4; ++mi)
        a[mi] = *(const short8*)(&As[half][(wm * 64 + mi * 16 + l15) * 32 + quad * 8]);
#pragma unroll
      for (int ni = 0; ni < 4; ++ni)
        b[ni] = *(const short8*)(&Bs[half][(wn * 64 + ni * 16 + l15) * 32 + quad * 8]);
#pragma unroll
      for (int mi = 0; mi < 4; ++mi)
#pragma unroll
        for (int ni = 0; ni < 4; ++ni)
          acc[mi][ni] = __builtin_amdgcn_mfma_f32_16x16x32_bf16(
              a[mi], b[ni], acc[mi][ni], 0, 0, 0);
    }
  }

#pragma unroll
  for (int mi = 0; mi < 4; ++mi)
#pragma unroll
    for (int ni = 0; ni < 4; ++ni)
#pragma unroll
      for (int r = 0; r < 4; ++r) {
        int row = m0 + wm * 64 + mi * 16 + quad * 4 + r;
        int col = n0 + wn * 64 + ni * 16 + l15;
        C[row * N3 + col] = __float2bfloat16(acc[mi][ni][r]);
      }
}

// ---------------------------------------------------------------------------
// Kernel 3: MFMA flash attention, fixed-max softmax (m=0).
// ROUND 9: back to 64-q tiles / 256 threads (grid 1024 = 4 blocks/CU; the
// 128-q/512-thread variant halved blocks/CU and regressed), PLUS:
//  * K/V staging software-pipelined: next block's global loads prefetched
//    into registers during compute, so the inter-barrier path is ds_write
//    only (the exposed ~200-900cyc load latency was ~55% of round-8 time).
//  * single unsigned-compare window mask; strength-reduced ALiBi bias.
//  * XCD-aware tile swizzle: 8 consecutive tiles (shared 512-row K/V
//    windows) land on one XCD's L2.
// l computed by MFMA via ones-row in Vt (dt=4). Ps wave-private, no barrier.
// LDS: Ks 9.2K + Vt 10.9K + Ps 9.2K + red 1K = 30.3 KB -> 4 blocks/CU.
// ---------------------------------------------------------------------------
__global__ __launch_bounds__(256, 4) void attn(
    const __hip_bfloat16* __restrict__ kqv,
    const unsigned short* __restrict__ xprobe,   // d_in[0], dtype probe only
    void* __restrict__ out) {
  __shared__ __align__(16) __hip_bfloat16 Ks[64 * 72];  // [k][d]
  __shared__ __align__(16) __hip_bfloat16 Vt[80 * 68];  // [d][key]; row 64 ones, 65..79 zero
  __shared__ __align__(16) __hip_bfloat16 Ps[64 * 72];  // [q][key] (wave-private strips)
  __shared__ float red[256];

  const int fl = detect_fp32<256>(xprobe, red);
  const int h  = blockIdx.y;
  const int bx = blockIdx.x;
  // swizzle: tiles (bx&7)*8 + (bx>>3); blocks with equal bx%8 (same XCD under
  // round-robin) get 8 consecutive tiles -> overlapping K/V windows in L2.
  const int i0 = 64 * ((bx & 7) * 8 + (bx >> 3));
  const int t    = threadIdx.x;
  const int wave = t >> 6, lane = t & 63;
  const int l15 = lane & 15, quad = lane >> 4;
  const float slope2  = exp2f(-0.5f * (float)(h + 1)) * LOG2E;  // m_h*log2(e)
  const float nslope2 = -slope2;                                // bias = nslope2*(i-j)
  const float qscale  = LOG2E / 32.0f;

  // ones/zero rows of Vt (staging only touches rows 0..63)
  for (int idx = t; idx < 16 * 68; idx += 256) {
    int rr = idx / 68, cc = idx - rr * 68;
    ((unsigned short*)Vt)[(64 + rr) * 68 + cc] = (rr == 0) ? 0x3F80 : 0;
  }

  // Q fragments direct to registers: A[m=l15][k=quad*8+j], rows wave*16+l15
  short8 aq[2];
#pragma unroll
  for (int ks2 = 0; ks2 < 2; ++ks2)
    aq[ks2] = *(const short8*)&kqv[(i0 + wave * 16 + l15) * N3 + DM + h * HD +
                                   ks2 * 32 + quad * 8];

  float4v o[5] = {};   // o[dt][r]: row quad*4+r, col dt*16+l15; dt=4 is l-column

  const int jlo  = max(0, i0 - WIN);       // 64-aligned
  const int nblk = (i0 + 64 - jlo) >> 6;   // <= 9

  // ---- staging geometry + prefetch of block 0 ----
  const int krow0 = t >> 3, krow1 = (t >> 3) + 32, kd0 = (t & 7) * 8;
  const int vr0 = (t >> 3) * 2, vd0 = (t & 7) * 8;
  uint4 kregA, kregB, vregA, vregB;
  kregA = *(const uint4*)&kqv[(jlo + krow0) * N3 + h * HD + kd0];
  kregB = *(const uint4*)&kqv[(jlo + krow1) * N3 + h * HD + kd0];
  vregA = *(const uint4*)&kqv[(jlo + vr0) * N3 + 2 * DM + h * HD + vd0];
  vregB = *(const uint4*)&kqv[(jlo + vr0 + 1) * N3 + 2 * DM + h * HD + vd0];

  for (int b = 0; b < nblk; ++b) {
    const int j0 = jlo + b * 64;
    __syncthreads();   // prev iter's K/V readers done before overwrite
    // ---- LDS fill from prefetched registers (short inter-barrier path) ----
    *(uint4*)&Ks[krow0 * 72 + kd0] = kregA;
    *(uint4*)&Ks[krow1 * 72 + kd0] = kregB;
    {
      const unsigned short* pa = (const unsigned short*)&vregA;
      const unsigned short* pb = (const unsigned short*)&vregB;
#pragma unroll
      for (int e = 0; e < 8; ++e) {
        unsigned int pack = (unsigned int)pa[e] | ((unsigned int)pb[e] << 16);
        *(unsigned int*)&Vt[(vd0 + e) * 68 + vr0] = pack;
      }
    }
    // ---- issue next block's prefetch (latency hidden behind compute) ----
    if (b + 1 < nblk) {
      const int jn = j0 + 64;
      kregA = *(const uint4*)&kqv[(jn + krow0) * N3 + h * HD + kd0];
      kregB = *(const uint4*)&kqv[(jn + krow1) * N3 + h * HD + kd0];
      vregA = *(const uint4*)&kqv[(jn + vr0) * N3 + 2 * DM + h * HD + vd0];
      vregB = *(const uint4*)&kqv[(jn + vr0 + 1) * N3 + 2 * DM + h * HD + vd0];
    }
    __syncthreads();

    // ---- S = Q*K^T : 4 n-tiles x 2 k-steps ----
    float4v sacc[4] = {};
#pragma unroll
    for (int ks2 = 0; ks2 < 2; ++ks2)
#pragma unroll
      for (int nt = 0; nt < 4; ++nt) {
        short8 bk = *(const short8*)&Ks[(nt * 16 + l15) * 72 + ks2 * 32 + quad * 8];
        sacc[nt] = __builtin_amdgcn_mfma_f32_16x16x32_bf16(aq[ks2], bk, sacc[nt], 0, 0, 0);
      }

    // ---- fixed-max softmax: p = exp2(x), masked -> 0 ----
    // rel(r,nt) = i - j = dbase + r - 16*nt;  bias = nslope2*rel (incremental)
    const int dbase = (i0 + wave * 16 + quad * 4) - (j0 + l15);
    const float s16 = nslope2 * -16.0f;   // bias step per nt
#pragma unroll
    for (int r = 0; r < 4; ++r) {
      float bias = nslope2 * (float)(dbase + r);
      int rel = dbase + r;
#pragma unroll
      for (int nt = 0; nt < 4; ++nt) {
        float x = fmaf(sacc[nt][r], qscale, bias);
        x = ((unsigned)rel <= (unsigned)WIN) ? x : -200.0f;  // exp2(-200)==0
        Ps[(wave * 16 + quad * 4 + r) * 72 + nt * 16 + l15] =
            __float2bfloat16(exp2f(x));
        bias += s16;
        rel -= 16;
      }
    }
    // no barrier: Ps strip is wave-private

    // ---- O += P*V (dt 0..3) ; l += P*1 (dt 4, ones-row of Vt) ----
#pragma unroll
    for (int ks = 0; ks < 64; ks += 32) {
      short8 ap = *(const short8*)&Ps[(wave * 16 + l15) * 72 + ks + quad * 8];
#pragma unroll
      for (int dt = 0; dt < 5; ++dt) {
        const __hip_bfloat16* vp = &Vt[(dt * 16 + l15) * 68 + ks + quad * 8];
        short4v v0 = *(const short4v*)vp;
        short4v v1 = *(const short4v*)(vp + 4);
        short8 bv = __builtin_shufflevector(v0, v1, 0, 1, 2, 3, 4, 5, 6, 7);
        o[dt] = __builtin_amdgcn_mfma_f32_16x16x32_bf16(ap, bv, o[dt], 0, 0, 0);
      }
    }
  }

  // ---- epilogue: l lives in o[4] col 0 (lane l15==0 of each quad group) ----
#pragma unroll
  for (int r = 0; r < 4; ++r) {
    const float l = __shfl(o[4][r], quad * 16, 64);   // broadcast from l15==0 lane
    const float inv_l = 1.0f / l;    // l >= 2^-2: diagonal key j=i always valid
    const int row = i0 + wave * 16 + quad * 4 + r;
#pragma unroll
    for (int dt = 0; dt < 4; ++dt) {
      const int idx = row * DM + h * HD + dt * 16 + l15;
      const float v = o[dt][r] * inv_l;
      if (fl) ((float*)out)[idx] = v;
      else    ((__hip_bfloat16*)out)[idx] = __float2bfloat16(v);
    }
  }
}

// ---------------------------------------------------------------------------
extern "C" void kernel_launch(void* const* d_in, const int* in_sizes, int n_in,
                              void* d_out, int out_size, void* d_ws, size_t ws_size,
                              hipStream_t stream) {
  char* ws = (char*)d_ws;
  __hip_bfloat16* wt  = (__hip_bfloat16*)(ws + 4096);          // 6 MB
  __hip_bfloat16* kqv = (__hip_bfloat16*)(ws + 4096 + 6291456);// 24 MB
  // xb lives in d_out's first 8 MB: dead until attn's epilogue overwrites all
  // of d_out, and gemm_kqv (the only xb reader) completes before attn runs.
  __hip_bfloat16* xb  = (__hip_bfloat16*)d_out;

  hipLaunchKernelGGL(prep, dim3(2048 + 768), dim3(256), 0, stream,
                     d_in[0], d_in[1], xb, wt);
  hipLaunchKernelGGL(gemm_kqv, dim3(24, 32), dim3(256), 0, stream, xb, wt, kqv);
  hipLaunchKernelGGL(attn, dim3(64, 16), dim3(256), 0, stream,
                     kqv, (const unsigned short*)d_in[0], d_out);
}